// Round 2
// baseline (350.406 us; speedup 1.0000x reference)
//
#include <hip/hip_runtime.h>

// Problem constants (fixed by reference setup_inputs)
#define BT    16384          // b*t = 4*4096
#define TSEQ  4096           // time steps per batch
#define DM    1024           // d_model
#define EXP   1024           // expanded
#define N1    2048           // 2*EXP
#define KDIM  1024           // GEMM K (both GEMMs)
#define EPSV  1e-8f

typedef __bf16 bf16x8 __attribute__((ext_vector_type(8)));
typedef float f32x16 __attribute__((ext_vector_type(16)));
typedef unsigned short u16x8 __attribute__((ext_vector_type(8)));

#define AS1CAST(p) ((__attribute__((address_space(1))) void*)(p))
#define AS3CAST(p) ((__attribute__((address_space(3))) void*)(p))

__device__ __forceinline__ unsigned short f2bf(float f) {
    unsigned int u = __float_as_uint(f);
    u += 0x7fffu + ((u >> 16) & 1u);
    return (unsigned short)(u >> 16);
}

// ---------------------------------------------------------------------------
// fp32 -> bf16 conversion, 4 elems/thread
__global__ __launch_bounds__(256) void k_f2bf(const float* __restrict__ in,
                                              unsigned short* __restrict__ out,
                                              int n4) {
    int i = blockIdx.x * 256 + threadIdx.x;
    if (i >= n4) return;
    float4 v = ((const float4*)in)[i];
    ushort4 o;
    o.x = f2bf(v.x); o.y = f2bf(v.y); o.z = f2bf(v.z); o.w = f2bf(v.w);
    ((ushort4*)out)[i] = o;
}

// ---------------------------------------------------------------------------
// bf16 GEMM, C[m,n] = sum_k A[m,k]*B[n,k] + bias[n]
// 128x128 tile / block, 256 thr = 4 waves in 2x2; each wave 64x64 as a
// 2x2 grid of 32x32x16 MFMA tiles (better FLOP/cyc than 16x16x32 — m119).
// Epilogue: per-row sumsq (shuffle-reduce + atomicAdd) for downstream RMSNorm.
template <int BF16_OUT>
__device__ __forceinline__ void gemm_body(const unsigned short* __restrict__ A,
                                          const unsigned short* __restrict__ Bw,
                                          const float* __restrict__ bias,
                                          unsigned short* __restrict__ Cb,
                                          float* __restrict__ Cf,
                                          float* __restrict__ ssq,
                                          int N) {
    __shared__ unsigned short sA[128 * 32];
    __shared__ unsigned short sB[128 * 32];

    const int tid  = threadIdx.x;
    const int lane = tid & 63;
    const int wv   = tid >> 6;
    const int wm   = wv >> 1, wn = wv & 1;
    const int row0 = blockIdx.y * 128, col0 = blockIdx.x * 128;

    // staging: 512 segments of 16B; thread covers segment tid and tid+256
    const int rA = tid >> 2, cA = (tid & 3) * 8;
    const unsigned short* aP = A  + (size_t)(row0 + rA) * KDIM + cA;
    const unsigned short* bP = Bw + (size_t)(col0 + rA) * KDIM + cA;
    unsigned short* lA0 = sA + (wv * 64) * 8;         // wave-uniform LDS dests
    unsigned short* lA1 = sA + (256 + wv * 64) * 8;
    unsigned short* lB0 = sB + (wv * 64) * 8;
    unsigned short* lB1 = sB + (256 + wv * 64) * 8;

    const int ln = lane & 31;      // row-within-32 for A/B operand
    const int hi = lane >> 5;      // k-half selector
    const int abase = (wm * 64 + ln) * 32 + hi * 8;
    const int bbase = (wn * 64 + ln) * 32 + hi * 8;

    f32x16 acc[2][2] = {};

    for (int kt = 0; kt < KDIM / 32; ++kt) {
        __syncthreads();
        const unsigned short* ap = aP + kt * 32;
        const unsigned short* bp = bP + kt * 32;
        __builtin_amdgcn_global_load_lds(AS1CAST(ap), AS3CAST(lA0), 16, 0, 0);
        __builtin_amdgcn_global_load_lds(AS1CAST(ap + (size_t)64 * KDIM), AS3CAST(lA1), 16, 0, 0);
        __builtin_amdgcn_global_load_lds(AS1CAST(bp), AS3CAST(lB0), 16, 0, 0);
        __builtin_amdgcn_global_load_lds(AS1CAST(bp + (size_t)64 * KDIM), AS3CAST(lB1), 16, 0, 0);
        __syncthreads();

        bf16x8 aF[2][2], bF[2][2];   // [tile][kstep]
#pragma unroll
        for (int i = 0; i < 2; ++i)
#pragma unroll
            for (int ks = 0; ks < 2; ++ks) {
                aF[i][ks] = *(const bf16x8*)&sA[abase + i * 32 * 32 + ks * 16];
                bF[i][ks] = *(const bf16x8*)&sB[bbase + i * 32 * 32 + ks * 16];
            }
#pragma unroll
        for (int ks = 0; ks < 2; ++ks)
#pragma unroll
            for (int i = 0; i < 2; ++i)
#pragma unroll
                for (int j = 0; j < 2; ++j)
                    acc[i][j] = __builtin_amdgcn_mfma_f32_32x32x16_bf16(
                        aF[i][ks], bF[j][ks], acc[i][j], 0, 0, 0);
    }

    // epilogue — C/D layout: col = lane&31, row = (reg&3) + 8*(reg>>2) + 4*(lane>>5)
    const int c0 = col0 + wn * 64 + ln;           // j=0 col; j=1 adds 32
    const float bs0 = bias[c0], bs1 = bias[c0 + 32];

#pragma unroll
    for (int i = 0; i < 2; ++i) {
        const int rbase = row0 + wm * 64 + i * 32 + 4 * hi;
#pragma unroll
        for (int reg = 0; reg < 16; ++reg) {
            const int gm = rbase + (reg & 3) + 8 * (reg >> 2);
            float v0 = acc[i][0][reg] + bs0;
            float v1 = acc[i][1][reg] + bs1;
            float p = v0 * v0 + v1 * v1;
#pragma unroll
            for (int off = 1; off < 32; off <<= 1) p += __shfl_xor(p, off, 64);
            if (ln == 0) atomicAdd(&ssq[gm], p);
            size_t base = (size_t)gm * N + c0;
            if (BF16_OUT) {
                Cb[base]      = f2bf(v0);
                Cb[base + 32] = f2bf(v1);
            } else {
                Cf[base]      = v0;
                Cf[base + 32] = v1;
            }
        }
    }
}

__global__ __launch_bounds__(256) void k_gemm_in(const unsigned short* __restrict__ A,
                                                 const unsigned short* __restrict__ Bw,
                                                 const float* __restrict__ bias,
                                                 unsigned short* __restrict__ Cb,
                                                 float* __restrict__ ssq) {
    gemm_body<1>(A, Bw, bias, Cb, nullptr, ssq, N1);
}

__global__ __launch_bounds__(256) void k_gemm_out(const unsigned short* __restrict__ A,
                                                  const unsigned short* __restrict__ Bw,
                                                  const float* __restrict__ bias,
                                                  float* __restrict__ Cf,
                                                  float* __restrict__ ssq) {
    gemm_body<0>(A, Bw, bias, nullptr, Cf, ssq, DM);
}

// ---------------------------------------------------------------------------
// RMSNorm(z) -> split x|v -> depthwise conv(K=3, same, per-batch) -> gate
// 2 tokens / block; 128 threads/token; 8 channels/thread.
__global__ __launch_bounds__(256) void k_conv_gate(const unsigned short* __restrict__ z,
                                                   const float* __restrict__ ssq1,
                                                   const float* __restrict__ inw,
                                                   const float* __restrict__ cw,
                                                   const float* __restrict__ cb,
                                                   unsigned short* __restrict__ g) {
    const int tok = blockIdx.x * 2 + (threadIdx.x >> 7);
    const int e8  = (threadIdx.x & 127) * 8;
    const int t   = tok & (TSEQ - 1);

    const float rs0 = rsqrtf(ssq1[tok] * (1.0f / N1) + EPSV);
    const int tm = (t > 0) ? tok - 1 : tok;
    const int tp = (t < TSEQ - 1) ? tok + 1 : tok;
    const float rsm = (t > 0) ? rsqrtf(ssq1[tm] * (1.0f / N1) + EPSV) : 0.0f;
    const float rsp = (t < TSEQ - 1) ? rsqrtf(ssq1[tp] * (1.0f / N1) + EPSV) : 0.0f;

    bf16x8 xm = *(const bf16x8*)(z + (size_t)tm * N1 + e8);
    bf16x8 x0 = *(const bf16x8*)(z + (size_t)tok * N1 + e8);
    bf16x8 xp = *(const bf16x8*)(z + (size_t)tp * N1 + e8);
    bf16x8 vv = *(const bf16x8*)(z + (size_t)tok * N1 + EXP + e8);

    u16x8 ov;
#pragma unroll
    for (int p = 0; p < 8; ++p) {
        const int e = e8 + p;
        const float we  = inw[e];
        const float wvv = inw[EXP + e];
        const float w0 = cw[e * 3], w1 = cw[e * 3 + 1], w2 = cw[e * 3 + 2];
        float y = w0 * ((float)xm[p] * rsm * we)
                + w1 * ((float)x0[p] * rs0 * we)
                + w2 * ((float)xp[p] * rsp * we)
                + cb[e];
        float vn = (float)vv[p] * rs0 * wvv;
        ov[p] = f2bf(vn * y);
    }
    *(u16x8*)(g + (size_t)tok * EXP + e8) = ov;
}

// ---------------------------------------------------------------------------
// Final RMSNorm scale in place on fp32 output: out *= rsqrt(mean)*w
__global__ __launch_bounds__(256) void k_outnorm(float* __restrict__ o,
                                                 const float* __restrict__ ssq2,
                                                 const float* __restrict__ onw) {
    const int idx = blockIdx.x * 256 + threadIdx.x;   // one float4
    const int tok = idx >> 8;                         // 256 float4 per token
    const int d4  = (idx & 255) * 4;
    const float rs = rsqrtf(ssq2[tok] * (1.0f / DM) + EPSV);
    float4 v = ((float4*)o)[idx];
    float4 w = *(const float4*)(onw + d4);
    v.x *= rs * w.x; v.y *= rs * w.y; v.z *= rs * w.z; v.w *= rs * w.w;
    ((float4*)o)[idx] = v;
}

// ---------------------------------------------------------------------------
extern "C" void kernel_launch(void* const* d_in, const int* in_sizes, int n_in,
                              void* d_out, int out_size, void* d_ws, size_t ws_size,
                              hipStream_t stream) {
    const float* u     = (const float*)d_in[0];
    const float* W_in  = (const float*)d_in[1];
    const float* b_in  = (const float*)d_in[2];
    const float* inw   = (const float*)d_in[3];
    const float* cw    = (const float*)d_in[4];
    const float* cb    = (const float*)d_in[5];
    const float* W_out = (const float*)d_in[6];
    const float* b_out = (const float*)d_in[7];
    const float* onw   = (const float*)d_in[8];
    float* out = (float*)d_out;

    char* ws = (char*)d_ws;
    unsigned short* u_bf    = (unsigned short*)ws; ws += (size_t)BT * DM * 2;     // 32 MB
    unsigned short* Win_bf  = (unsigned short*)ws; ws += (size_t)N1 * DM * 2;     //  4 MB
    unsigned short* Wout_bf = (unsigned short*)ws; ws += (size_t)DM * EXP * 2;    //  2 MB
    unsigned short* z_bf    = (unsigned short*)ws; ws += (size_t)BT * N1 * 2;     // 64 MB
    unsigned short* g_bf    = (unsigned short*)ws; ws += (size_t)BT * EXP * 2;    // 32 MB
    float* ssq1 = (float*)ws; ws += (size_t)BT * 4;
    float* ssq2 = (float*)ws; ws += (size_t)BT * 4;

    hipMemsetAsync(ssq1, 0, (size_t)BT * 2 * sizeof(float), stream);  // ssq1+ssq2 adjacent

    k_f2bf<<<(BT * DM / 4 + 255) / 256, 256, 0, stream>>>(u, u_bf, BT * DM / 4);
    k_f2bf<<<(N1 * DM / 4 + 255) / 256, 256, 0, stream>>>(W_in, Win_bf, N1 * DM / 4);
    k_f2bf<<<(DM * EXP / 4 + 255) / 256, 256, 0, stream>>>(W_out, Wout_bf, DM * EXP / 4);

    dim3 gA(N1 / 128, BT / 128);   // (16,128)
    k_gemm_in<<<gA, 256, 0, stream>>>(u_bf, Win_bf, b_in, z_bf, ssq1);

    k_conv_gate<<<BT / 2, 256, 0, stream>>>(z_bf, ssq1, inw, cw, cb, g_bf);

    dim3 gC(DM / 128, BT / 128);   // (8,128)
    k_gemm_out<<<gC, 256, 0, stream>>>(g_bf, Wout_bf, b_out, out, ssq2);

    k_outnorm<<<BT, 256, 0, stream>>>(out, ssq2, onw);

    (void)in_sizes; (void)n_in; (void)out_size; (void)ws_size;
}

// Round 3
// 324.157 us; speedup vs baseline: 1.0810x; 1.0810x over previous
//
#include <hip/hip_runtime.h>

// Problem constants (fixed by reference setup_inputs)
#define BT    16384          // b*t = 4*4096
#define TSEQ  4096           // time steps per batch
#define DM    1024           // d_model
#define EXP   1024           // expanded
#define N1    2048           // 2*EXP
#define KDIM  1024           // GEMM K (both GEMMs)
#define EPSV  1e-8f

typedef __bf16 bf16x8 __attribute__((ext_vector_type(8)));
typedef float f32x16 __attribute__((ext_vector_type(16)));
typedef unsigned short u16x8 __attribute__((ext_vector_type(8)));

#define AS1CAST(p) ((__attribute__((address_space(1))) void*)(p))
#define AS3CAST(p) ((__attribute__((address_space(3))) void*)(p))

__device__ __forceinline__ unsigned short f2bf(float f) {
    unsigned int u = __float_as_uint(f);
    u += 0x7fffu + ((u >> 16) & 1u);
    return (unsigned short)(u >> 16);
}

// ---------------------------------------------------------------------------
// fp32 -> bf16 conversion for all three inputs in ONE launch (4 elems/thread).
__global__ __launch_bounds__(256) void k_f2bf3(const float* __restrict__ i0, unsigned short* __restrict__ o0, int n0,
                                               const float* __restrict__ i1, unsigned short* __restrict__ o1, int n1,
                                               const float* __restrict__ i2, unsigned short* __restrict__ o2, int n2) {
    int i = blockIdx.x * 256 + threadIdx.x;
    const float* in; unsigned short* out;
    if (i < n0)                { in = i0; out = o0; }
    else if (i < n0 + n1)      { in = i1; out = o1; i -= n0; }
    else if (i < n0 + n1 + n2) { in = i2; out = o2; i -= n0 + n1; }
    else return;
    float4 v = ((const float4*)in)[i];
    ushort4 o;
    o.x = f2bf(v.x); o.y = f2bf(v.y); o.z = f2bf(v.z); o.w = f2bf(v.w);
    ((ushort4*)out)[i] = o;
}

// ---------------------------------------------------------------------------
// bf16 GEMM, C[m,n] = sum_k A[m,k]*B[n,k] + bias[n]
// 128x128 tile / block, 256 thr = 4 waves in 2x2; each wave 64x64 as a
// 2x2 grid of 32x32x16 MFMA tiles. BK=64 K-tile (16 barrier pairs).
// LDS layout: rows of 64 elems (128 B); 16B-quarter q of row r stored at
// physical slot (q+r)&7 -> operand reads hit the minimal 8-access bank
// pattern instead of the 16-way conflict of row-major (round-2 regression).
// Epilogue: per-row sumsq (shuffle-reduce + atomicAdd) for downstream RMSNorm.
template <int BF16_OUT>
__device__ __forceinline__ void gemm_body(const unsigned short* __restrict__ A,
                                          const unsigned short* __restrict__ Bw,
                                          const float* __restrict__ bias,
                                          unsigned short* __restrict__ Cb,
                                          float* __restrict__ Cf,
                                          float* __restrict__ ssq,
                                          int N) {
    __shared__ unsigned short sA[128 * 64];   // 16 KB
    __shared__ unsigned short sB[128 * 64];   // 16 KB

    const int tid  = threadIdx.x;
    const int lane = tid & 63;
    const int wv   = tid >> 6;
    const int wm   = wv >> 1, wn = wv & 1;
    const int row0 = blockIdx.y * 128, col0 = blockIdx.x * 128;

    // staging: 1024 physical 16B slots per matrix; batch b covers slots
    // s = b*256 + tid.  row = s>>3, phys-quarter p = tid&7,
    // logical quarter q = (p - row) & 7.
    const int p7 = tid & 7;
    const unsigned short* aPtr[4];
    const unsigned short* bPtr[4];
#pragma unroll
    for (int b = 0; b < 4; ++b) {
        const int r = (b * 256 + tid) >> 3;
        const int q = (p7 - r) & 7;
        aPtr[b] = A  + (size_t)(row0 + r) * KDIM + q * 8;
        bPtr[b] = Bw + (size_t)(col0 + r) * KDIM + q * 8;
    }
    // wave-uniform LDS dests (base + lane*16B)
    unsigned short* lA[4];
    unsigned short* lB[4];
#pragma unroll
    for (int b = 0; b < 4; ++b) {
        lA[b] = sA + (b * 256 + wv * 64) * 8;
        lB[b] = sB + (b * 256 + wv * 64) * 8;
    }

    const int ln = lane & 31;      // operand row within 32
    const int hi = lane >> 5;      // k-half selector
    const int arow0 = (wm * 64 + ln) * 64;     // element base, A tile i=0
    const int brow0 = (wn * 64 + ln) * 64;

    f32x16 acc[2][2] = {};

    for (int kt = 0; kt < KDIM / 64; ++kt) {
        __syncthreads();
#pragma unroll
        for (int b = 0; b < 4; ++b) {
            __builtin_amdgcn_global_load_lds(AS1CAST(aPtr[b] + kt * 64), AS3CAST(lA[b]), 16, 0, 0);
            __builtin_amdgcn_global_load_lds(AS1CAST(bPtr[b] + kt * 64), AS3CAST(lB[b]), 16, 0, 0);
        }
        __syncthreads();

#pragma unroll
        for (int ks = 0; ks < 4; ++ks) {
            const int sw = (((ks * 2 + hi) + ln) & 7) * 8;   // swizzled quarter offset
            bf16x8 aF[2], bF[2];
#pragma unroll
            for (int i = 0; i < 2; ++i) {
                aF[i] = *(const bf16x8*)&sA[arow0 + i * 32 * 64 + sw];
                bF[i] = *(const bf16x8*)&sB[brow0 + i * 32 * 64 + sw];
            }
#pragma unroll
            for (int i = 0; i < 2; ++i)
#pragma unroll
                for (int j = 0; j < 2; ++j)
                    acc[i][j] = __builtin_amdgcn_mfma_f32_32x32x16_bf16(
                        aF[i], bF[j], acc[i][j], 0, 0, 0);
        }
    }

    // epilogue — C/D layout: col = lane&31, row = (reg&3) + 8*(reg>>2) + 4*(lane>>5)
    const int c0 = col0 + wn * 64 + ln;           // j=0 col; j=1 adds 32
    const float bs0 = bias[c0], bs1 = bias[c0 + 32];

#pragma unroll
    for (int i = 0; i < 2; ++i) {
        const int rbase = row0 + wm * 64 + i * 32 + 4 * hi;
#pragma unroll
        for (int reg = 0; reg < 16; ++reg) {
            const int gm = rbase + (reg & 3) + 8 * (reg >> 2);
            float v0 = acc[i][0][reg] + bs0;
            float v1 = acc[i][1][reg] + bs1;
            float p = v0 * v0 + v1 * v1;
#pragma unroll
            for (int off = 1; off < 32; off <<= 1) p += __shfl_xor(p, off, 64);
            if (ln == 0) atomicAdd(&ssq[gm], p);
            size_t base = (size_t)gm * N + c0;
            if (BF16_OUT) {
                Cb[base]      = f2bf(v0);
                Cb[base + 32] = f2bf(v1);
            } else {
                Cf[base]      = v0;
                Cf[base + 32] = v1;
            }
        }
    }
}

__global__ __launch_bounds__(256) void k_gemm_in(const unsigned short* __restrict__ A,
                                                 const unsigned short* __restrict__ Bw,
                                                 const float* __restrict__ bias,
                                                 unsigned short* __restrict__ Cb,
                                                 float* __restrict__ ssq) {
    gemm_body<1>(A, Bw, bias, Cb, nullptr, ssq, N1);
}

__global__ __launch_bounds__(256) void k_gemm_out(const unsigned short* __restrict__ A,
                                                  const unsigned short* __restrict__ Bw,
                                                  const float* __restrict__ bias,
                                                  float* __restrict__ Cf,
                                                  float* __restrict__ ssq) {
    gemm_body<0>(A, Bw, bias, nullptr, Cf, ssq, DM);
}

// ---------------------------------------------------------------------------
// RMSNorm(z) -> split x|v -> depthwise conv(K=3, same, per-batch) -> gate
// 2 tokens / block; 128 threads/token; 8 channels/thread.
__global__ __launch_bounds__(256) void k_conv_gate(const unsigned short* __restrict__ z,
                                                   const float* __restrict__ ssq1,
                                                   const float* __restrict__ inw,
                                                   const float* __restrict__ cw,
                                                   const float* __restrict__ cb,
                                                   unsigned short* __restrict__ g) {
    const int tok = blockIdx.x * 2 + (threadIdx.x >> 7);
    const int e8  = (threadIdx.x & 127) * 8;
    const int t   = tok & (TSEQ - 1);

    const float rs0 = rsqrtf(ssq1[tok] * (1.0f / N1) + EPSV);
    const int tm = (t > 0) ? tok - 1 : tok;
    const int tp = (t < TSEQ - 1) ? tok + 1 : tok;
    const float rsm = (t > 0) ? rsqrtf(ssq1[tm] * (1.0f / N1) + EPSV) : 0.0f;
    const float rsp = (t < TSEQ - 1) ? rsqrtf(ssq1[tp] * (1.0f / N1) + EPSV) : 0.0f;

    bf16x8 xm = *(const bf16x8*)(z + (size_t)tm * N1 + e8);
    bf16x8 x0 = *(const bf16x8*)(z + (size_t)tok * N1 + e8);
    bf16x8 xp = *(const bf16x8*)(z + (size_t)tp * N1 + e8);
    bf16x8 vv = *(const bf16x8*)(z + (size_t)tok * N1 + EXP + e8);

    u16x8 ov;
#pragma unroll
    for (int p = 0; p < 8; ++p) {
        const int e = e8 + p;
        const float we  = inw[e];
        const float wvv = inw[EXP + e];
        const float w0 = cw[e * 3], w1 = cw[e * 3 + 1], w2 = cw[e * 3 + 2];
        float y = w0 * ((float)xm[p] * rsm * we)
                + w1 * ((float)x0[p] * rs0 * we)
                + w2 * ((float)xp[p] * rsp * we)
                + cb[e];
        float vn = (float)vv[p] * rs0 * wvv;
        ov[p] = f2bf(vn * y);
    }
    *(u16x8*)(g + (size_t)tok * EXP + e8) = ov;
}

// ---------------------------------------------------------------------------
// Final RMSNorm scale in place on fp32 output: out *= rsqrt(mean)*w
__global__ __launch_bounds__(256) void k_outnorm(float* __restrict__ o,
                                                 const float* __restrict__ ssq2,
                                                 const float* __restrict__ onw) {
    const int idx = blockIdx.x * 256 + threadIdx.x;   // one float4
    const int tok = idx >> 8;                         // 256 float4 per token
    const int d4  = (idx & 255) * 4;
    const float rs = rsqrtf(ssq2[tok] * (1.0f / DM) + EPSV);
    float4 v = ((float4*)o)[idx];
    float4 w = *(const float4*)(onw + d4);
    v.x *= rs * w.x; v.y *= rs * w.y; v.z *= rs * w.z; v.w *= rs * w.w;
    ((float4*)o)[idx] = v;
}

// ---------------------------------------------------------------------------
extern "C" void kernel_launch(void* const* d_in, const int* in_sizes, int n_in,
                              void* d_out, int out_size, void* d_ws, size_t ws_size,
                              hipStream_t stream) {
    const float* u     = (const float*)d_in[0];
    const float* W_in  = (const float*)d_in[1];
    const float* b_in  = (const float*)d_in[2];
    const float* inw   = (const float*)d_in[3];
    const float* cw    = (const float*)d_in[4];
    const float* cb    = (const float*)d_in[5];
    const float* W_out = (const float*)d_in[6];
    const float* b_out = (const float*)d_in[7];
    const float* onw   = (const float*)d_in[8];
    float* out = (float*)d_out;

    char* ws = (char*)d_ws;
    unsigned short* u_bf    = (unsigned short*)ws; ws += (size_t)BT * DM * 2;     // 32 MB
    unsigned short* Win_bf  = (unsigned short*)ws; ws += (size_t)N1 * DM * 2;     //  4 MB
    unsigned short* Wout_bf = (unsigned short*)ws; ws += (size_t)DM * EXP * 2;    //  2 MB
    unsigned short* z_bf    = (unsigned short*)ws; ws += (size_t)BT * N1 * 2;     // 64 MB
    unsigned short* g_bf    = (unsigned short*)ws; ws += (size_t)BT * EXP * 2;    // 32 MB
    float* ssq1 = (float*)ws; ws += (size_t)BT * 4;
    float* ssq2 = (float*)ws; ws += (size_t)BT * 4;

    hipMemsetAsync(ssq1, 0, (size_t)BT * 2 * sizeof(float), stream);  // ssq1+ssq2 adjacent

    const int n0 = BT * DM / 4, n1c = N1 * DM / 4, n2c = DM * EXP / 4;
    k_f2bf3<<<(n0 + n1c + n2c + 255) / 256, 256, 0, stream>>>(u, u_bf, n0,
                                                              W_in, Win_bf, n1c,
                                                              W_out, Wout_bf, n2c);

    dim3 gA(N1 / 128, BT / 128);   // (16,128)
    k_gemm_in<<<gA, 256, 0, stream>>>(u_bf, Win_bf, b_in, z_bf, ssq1);

    k_conv_gate<<<BT / 2, 256, 0, stream>>>(z_bf, ssq1, inw, cw, cb, g_bf);

    dim3 gC(DM / 128, BT / 128);   // (8,128)
    k_gemm_out<<<gC, 256, 0, stream>>>(g_bf, Wout_bf, b_out, out, ssq2);

    k_outnorm<<<BT, 256, 0, stream>>>(out, ssq2, onw);

    (void)in_sizes; (void)n_in; (void)out_size; (void)ws_size;
}